// Round 8
// baseline (12318.808 us; speedup 1.0000x reference)
//
#include <hip/hip_runtime.h>
#include <hip/hip_bf16.h>
#include <math.h>

typedef short bfrag8 __attribute__((ext_vector_type(8)));   // 8 bf16 (4 VGPRs)
typedef float facc4  __attribute__((ext_vector_type(4)));   // MFMA accumulator

#define BATCH   128
#define TSTEPS  256
#define UNITS   1024
#define SPIN_GUARD (1u << 24)

// ---------------------------------------------------------------------------
// Weight-stationary (persistent-RNN) layer-pipelined GRU stack.
// Round-4 evidence: per-step acquire fence invalidates L2 -> 31MB/step weight
// refetch. Fix: weights live in VGPRs (invalidation-immune).
// Rounds 5-7 failed with stub-identical absmax: hipLaunchCooperativeKernel
// silently REJECTED (occupancy query returns 0 for ~480-VGPR waves; LDS was
// exonerated by r7's 67.5KB failure). Kernel has no grid.sync since r4 ->
// plain <<<256,256>>> launch (1 WG/CU co-residency by capacity arithmetic).
//
// Per WG (l, nt): output tile = 128 m x 64 B-rows (16 units x 4 gates).
// 4 waves = 4 K-quarters (K=2048 -> 512/wave; l0: K=1152 -> 288/wave).
//   wave q holds weights B[64 rows][K/4] in 256 VGPRs (wreg[16][4] bfrag8),
//   loads its A-slice fragments straight to VGPRs (round-4-proven pattern),
//   accumulates a full [128x64] fp32 partial; C exchanged via LDS in halves
//   (two 64-row phases, LDS 67584 B).
//
// Weight pack per layer: [nt(64)][q(4)][kk(KK)][fb(4)][lane(64)][8 bf16]
//   lane -> B[row = fb*16 + (lane&15)][k = q*KQ + kk*32 + (lane>>4)*8 + e]
//   B-row r (0..63): blk=r>>5, g=(r>>3)&3, e=r&7 -> unit u = nt*16+blk*8+e
//   gate g: 0=z (Wx+Wh), 1=r, 2=xh (Wx, k<Din), 3=rh (Wh, k>=Din)
// A (x / h state) chunk-major: [k-group kg][m(128)][8 bf16]
// Sync: round-4 dataflow protocol (per-layer gen counters) + bounded spins.
// ---------------------------------------------------------------------------

struct Sync {              // one 256B cacheline per counter
  unsigned int cnt[4][64];
  unsigned int gen[4][64];
};

struct GArgs {
  const __hip_bfloat16* xin;      // [T][16 kc][128][8] layer-0 input
  const __hip_bfloat16* Wp[4];    // packed weights (layout above)
  const float* pb;                // packed biases [4][4096] (B-row order)
  __hip_bfloat16* hout;           // h ring [4 layer][4 slot][128 kc][128][8]
  float* hfin;                    // fp32 final h of layer 3 [128][1024]
  Sync* sy;
  const float* Wd;                // [1024]
  const float* bd;                // [1]
  float* out;                     // [128]
};

// ---------------------------------------------------------------------------
__global__ void prep_xin(const float* __restrict__ in, __hip_bfloat16* __restrict__ xin) {
  const int idx = blockIdx.x * 256 + threadIdx.x;    // chunk id: (t, kg, m)
  if (idx >= TSTEPS * 16 * 128) return;
  const int m  = idx & 127;
  const int kg = (idx >> 7) & 15;
  const int t  = idx >> 11;
  union { __hip_bfloat16 h[8]; uint4 v; } o;
  const float* src = in + ((size_t)m * TSTEPS + t) * 128 + (kg << 3);
  #pragma unroll
  for (int e = 0; e < 8; ++e) o.h[e] = __float2bfloat16(src[e]);
  ((uint4*)xin)[idx] = o.v;
}

__global__ void prep_w(const float* __restrict__ Wx, const float* __restrict__ Wh,
                       int Din, int KS, int KK, int KQ,
                       __hip_bfloat16* __restrict__ W) {
  const int p   = blockIdx.x;              // global B-row, 0..4095
  const int tid = threadIdx.x;             // k-group along K
  const int k0  = tid << 3;
  if (k0 >= KS) return;
  const int nt = p >> 6, r = p & 63;
  const int fb = r >> 4, rl = r & 15;
  const int gg = (r >> 3) & 3, eu = r & 7;
  const int u   = nt * 16 + (r >> 5) * 8 + eu;
  const int col = (gg == 0) ? u : (gg == 1) ? (1024 + u) : (2048 + u);
  const int q  = k0 / KQ;
  const int kw = k0 - q * KQ;
  const int kk = kw >> 5, ku = (kw >> 3) & 3;
  const int lane = ku * 16 + rl;
  union { __hip_bfloat16 h[8]; uint4 v; } o;
  #pragma unroll
  for (int e = 0; e < 8; ++e) {
    const int k = k0 + e;
    float v = 0.0f;
    if (k < Din) { if (gg != 3) v = Wx[(size_t)k * 3072 + col]; }
    else         { if (gg != 2) v = Wh[(size_t)(k - Din) * 3072 + col]; }
    o.h[e] = __float2bfloat16(v);
  }
  const size_t idx16 = ((size_t)(((nt * 4 + q) * KK + kk) * 4 + fb)) * 64 + lane;
  ((uint4*)W)[idx16] = o.v;
}

struct BiasArgs { const float* bx[4]; const float* bh[4]; float* pb; };

__global__ void prep_bias(BiasArgs ba) {
  const int idx = blockIdx.x * 256 + threadIdx.x;    // l*4096 + p
  if (idx >= 4 * 4096) return;
  const int p = idx & 4095, l = idx >> 12;
  const int nt = p >> 6, r = p & 63;
  const int uh = r >> 5, g = (r >> 3) & 3, eu = r & 7;
  const int u = nt * 16 + uh * 8 + eu;
  const float* bx = ba.bx[l];
  const float* bh = ba.bh[l];
  float v;
  if (g == 0)      v = bx[u] + bh[u];
  else if (g == 1) v = bx[1024 + u] + bh[1024 + u];
  else if (g == 2) v = bx[2048 + u];
  else             v = bh[2048 + u];
  ba.pb[idx] = v;
}

__global__ void prep_zero(__hip_bfloat16* hout, Sync* sy) {
  const int b = blockIdx.x;
  if (b < 1024) {                          // hout: 4*4*128*1024*2B = 262144 uint4
    const uint4 z4 = {0, 0, 0, 0};
    ((uint4*)hout)[b * 256 + threadIdx.x] = z4;
  } else {                                 // sync counters
    unsigned int* p = (unsigned int*)sy;   // 512 uints
    #pragma unroll
    for (int i = 0; i < 2; ++i) p[i * 256 + threadIdx.x] = 0u;
  }
}

// ---------------------------------------------------------------------------
__global__ __launch_bounds__(256, 1) void gru_pipe(GArgs g) {
  __shared__ float lsC[4 * 4224];          // 4 C-regions [64][66] f32 = 67584 B

  const int tid  = threadIdx.x;
  const int lane = tid & 63;
  const int q    = tid >> 6;               // wave = K-quarter
  const int wg = blockIdx.x;
  const int l  = (wg & 7) >> 1;            // layer 0..3 (XCD-pair adjacency)
  const int nt = ((wg >> 3) << 1) | (wg & 1);   // n-tile 0..63 (16 units)
  const int KKc   = l ? 16 : 9;            // k-chunks (32 k) per wave
  const int DINC8 = l ? 128 : 16;          // x-part k-groups (Din/8)
  const int qKQ8  = q * (l ? 64 : 36);     // wave's first k-group
  const float* pbL = g.pb + (l << 12) + (nt << 6);
  const int rl = lane & 15;
  const int kq = lane >> 4;                // k-unit within 32-k chunk

  // heartbeat: distinguishes "never launched" (0) from "died mid-kernel" (-1)
  if (wg < BATCH && tid == 0) g.out[wg] = -1.0f;

  // ---- persistent weight registers: 64 rows x K/4 per wave (256 VGPR) ----
  bfrag8 wreg[16][4];
  {
    const char* wb = (const char*)g.Wp[l] + ((size_t)(nt * 4 + q) * KKc) * 4096;
    #pragma unroll
    for (int kk = 0; kk < 16; ++kk)
      if (kk < KKc)
        #pragma unroll
        for (int fb = 0; fb < 4; ++fb)
          wreg[kk][fb] = *(const bfrag8*)(wb + (kk * 4 + fb) * 1024 + lane * 16);
  }

  // per-fa byte offsets within a chunk's [128 m][8 bf16] block
  int aoff[8];
  #pragma unroll
  for (int fa = 0; fa < 8; ++fa) aoff[fa] = (fa * 16 + rl) * 16;

  // persistent fp32 h-state: thread (pm=tid&127, blk=tid>>7) owns units
  // nt*16 + blk*8 + 0..7 of batch row pm — private across the whole t-loop.
  float hfr[8];
  #pragma unroll
  for (int e = 0; e < 8; ++e) hfr[e] = 0.0f;
  const int pm  = tid & 127;
  const int blk = tid >> 7;

  unsigned int* cnt  = &g.sy->cnt[l][0];
  unsigned int* genL = &g.sy->gen[l][0];
  unsigned int* genU = (l > 0) ? &g.sy->gen[l - 1][0] : nullptr;
  unsigned int* genD = (l < 3) ? &g.sy->gen[l + 1][0] : nullptr;

  const size_t CH = 128 * 1024;            // elements per h slot

  for (int t = 0; t < TSTEPS; ++t) {
    { // --- dataflow spin: 3 parallel pollers (bounded), one acquire fence ---
      unsigned int gd = 0;
      if (tid == 0) {
        while (__hip_atomic_load(genL, __ATOMIC_RELAXED, __HIP_MEMORY_SCOPE_AGENT)
               < (unsigned)t) { if (++gd > SPIN_GUARD) break; __builtin_amdgcn_s_sleep(4); }
      } else if (tid == 1 && genU) {
        while (__hip_atomic_load(genU, __ATOMIC_RELAXED, __HIP_MEMORY_SCOPE_AGENT)
               < (unsigned)(t + 1)) { if (++gd > SPIN_GUARD) break; __builtin_amdgcn_s_sleep(4); }
      } else if (tid == 2 && genD && t >= 4) {
        while (__hip_atomic_load(genD, __ATOMIC_RELAXED, __HIP_MEMORY_SCOPE_AGENT)
               < (unsigned)(t - 3)) { if (++gd > SPIN_GUARD) break; __builtin_amdgcn_s_sleep(4); }
      }
      __syncthreads();
      if (tid == 0) __builtin_amdgcn_fence(__ATOMIC_ACQUIRE, "agent");
      __syncthreads();
    }

    const char* hA = (const char*)(g.hout + (size_t)((l << 2) | ((t + 3) & 3)) * CH);
    const char* xA = (const char*)(l
        ? (g.hout + (size_t)(((l - 1) << 2) | (t & 3)) * CH)
        : (g.xin + (size_t)t * (16 * 128 * 8)));

    bfrag8 aP[8], aQ[8];

    // load one chunk's 8 A-fragments (rows fa*16+rl, k-group qKQ8+KK_*4+kq)
    #define LOADA(AR, KK_)                                                   \
      {                                                                      \
        const int kg = qKQ8 + (KK_) * 4 + kq;                                \
        const char* srcb = (kg < DINC8)                                      \
            ? (xA + (size_t)kg * 2048)                                       \
            : (hA + (size_t)(kg - DINC8) * 2048);                            \
        _Pragma("unroll")                                                    \
        for (int fa = 0; fa < 8; ++fa)                                       \
          AR[fa] = *(const bfrag8*)(srcb + aoff[fa]);                        \
      }

    #define DOMFMA(AR, KK_)                                                  \
      _Pragma("unroll")                                                      \
      for (int fa = 0; fa < 8; ++fa)                                         \
        _Pragma("unroll")                                                    \
        for (int fb = 0; fb < 4; ++fb)                                       \
          acc[fa][fb] = __builtin_amdgcn_mfma_f32_16x16x32_bf16(             \
              AR[fa], wreg[KK_][fb], acc[fa][fb], 0, 0, 0);

    facc4 acc[8][4];
    #pragma unroll
    for (int fa = 0; fa < 8; ++fa)
      #pragma unroll
      for (int fb = 0; fb < 4; ++fb)
        acc[fa][fb] = (facc4){0, 0, 0, 0};

    LOADA(aP, 0);
    if (l) {
      #pragma unroll
      for (int kk = 0; kk < 16; kk += 2) {
        LOADA(aQ, kk + 1);
        DOMFMA(aP, kk);
        if (kk + 2 < 16) LOADA(aP, kk + 2);
        DOMFMA(aQ, kk + 1);
      }
    } else {
      #pragma unroll
      for (int kk = 0; kk < 8; kk += 2) {
        LOADA(aQ, kk + 1);
        DOMFMA(aP, kk);
        LOADA(aP, kk + 2);
        DOMFMA(aQ, kk + 1);
      }
      DOMFMA(aP, 8);
    }
    #undef LOADA
    #undef DOMFMA

    // ---- C exchange + pointwise, two 64-row phases (LDS = 67.6 KB) ----
    __hip_bfloat16* houtW = g.hout + (size_t)((l << 2) | (t & 3)) * CH;

    #define CWRITE(HALF_)                                                    \
      {                                                                      \
        float* Cq = lsC + q * 4224;                                          \
        _Pragma("unroll")                                                    \
        for (int fa = 0; fa < 4; ++fa) {                                     \
          const int crow = (fa << 4) + ((lane >> 4) << 2);                   \
          _Pragma("unroll")                                                  \
          for (int fb = 0; fb < 4; ++fb) {                                   \
            const int ccol = (fb << 4) + rl;                                 \
            _Pragma("unroll")                                                \
            for (int j = 0; j < 4; ++j)                                      \
              Cq[(crow + j) * 66 + ccol] = acc[fa + 4 * (HALF_)][fb][j];     \
          }                                                                  \
        }                                                                    \
      }

    #define POINTWISE(ROW_)                                                  \
      {                                                                      \
        const float* Cb = lsC + (ROW_) * 66 + blk * 32;                      \
        const float* pbb = pbL + blk * 32;                                   \
        union { __hip_bfloat16 h[8]; uint4 v; } ou;                          \
        _Pragma("unroll")                                                    \
        for (int e = 0; e < 8; ++e) {                                        \
          float gz  = Cb[e]      + pbb[e];                                   \
          float gr  = Cb[8 + e]  + pbb[8 + e];                               \
          float gxh = Cb[16 + e] + pbb[16 + e];                              \
          float grh = Cb[24 + e] + pbb[24 + e];                              \
          _Pragma("unroll")                                                  \
          for (int qq = 1; qq < 4; ++qq) {                                   \
            gz  += Cb[qq * 4224 + e];                                        \
            gr  += Cb[qq * 4224 + 8 + e];                                    \
            gxh += Cb[qq * 4224 + 16 + e];                                   \
            grh += Cb[qq * 4224 + 24 + e];                                   \
          }                                                                  \
          const float z = 1.0f / (1.0f + __expf(-gz));                       \
          const float r = 1.0f / (1.0f + __expf(-gr));                       \
          const float e2 = __expf(2.0f * (gxh + r * grh));                   \
          const float hh = 1.0f - 2.0f / (e2 + 1.0f);   /* tanh */           \
          const float hn = z * hfr[e] + (1.0f - z) * hh;                     \
          hfr[e] = hn;                                                       \
          ou.h[e] = __float2bfloat16(hn);                                    \
        }                                                                    \
        ((uint4*)houtW)[(nt * 2 + blk) * 128 + pm] = ou.v;                   \
        if (l == 3 && t == TSTEPS - 1) {                                     \
          float* dst = g.hfin + (size_t)pm * 1024 + (nt << 4) + (blk << 3);  \
          _Pragma("unroll")                                                  \
          for (int e = 0; e < 8; ++e) dst[e] = hfr[e];                       \
        }                                                                    \
      }

    CWRITE(0);                             // partial rows 0..63
    __syncthreads();
    if (pm < 64) POINTWISE(pm);
    __syncthreads();
    CWRITE(1);                             // partial rows 64..127
    __syncthreads();
    if (pm >= 64) POINTWISE(pm - 64);
    __syncthreads();                       // all stores drained (per-wave vmcnt)

    #undef CWRITE
    #undef POINTWISE

    if (tid == 0) {                        // arrive: release + publish
      __builtin_amdgcn_fence(__ATOMIC_RELEASE, "agent");
      unsigned int old = __hip_atomic_fetch_add(cnt, 1u, __ATOMIC_RELAXED,
                                                __HIP_MEMORY_SCOPE_AGENT);
      if (old == (unsigned)(64 * (t + 1) - 1))
        __hip_atomic_store(genL, (unsigned)(t + 1), __ATOMIC_RELEASE,
                           __HIP_MEMORY_SCOPE_AGENT);
    }
  }

  // dense head: out[b] = hfin[b][:] . Wd + bd
  if (wg < BATCH) {
    if (tid == 0) {
      unsigned int gd = 0;
      while (__hip_atomic_load(&g.sy->gen[3][0], __ATOMIC_RELAXED,
                               __HIP_MEMORY_SCOPE_AGENT) < (unsigned)TSTEPS)
        { if (++gd > SPIN_GUARD) break; __builtin_amdgcn_s_sleep(4); }
      __builtin_amdgcn_fence(__ATOMIC_ACQUIRE, "agent");
    }
    __syncthreads();
    const float* h = g.hfin + (size_t)wg * 1024;
    float ssum = 0.0f;
    for (int u = tid; u < UNITS; u += 256) ssum += h[u] * g.Wd[u];
    lsC[tid] = ssum;
    __syncthreads();
    for (int off = 128; off; off >>= 1) {
      if (tid < off) lsC[tid] += lsC[tid + off];
      __syncthreads();
    }
    if (tid == 0) g.out[wg] = lsC[0] + g.bd[0];
  }
}

// ---------------------------------------------------------------------------
extern "C" void kernel_launch(void* const* d_in, const int* in_sizes, int n_in,
                              void* d_out, int out_size, void* d_ws, size_t ws_size,
                              hipStream_t stream) {
  (void)in_sizes; (void)n_in; (void)out_size; (void)ws_size;
  const float* inputs = (const float*)d_in[0];
  const float* Wx[4] = {(const float*)d_in[1], (const float*)d_in[5], (const float*)d_in[9],  (const float*)d_in[13]};
  const float* Wh[4] = {(const float*)d_in[2], (const float*)d_in[6], (const float*)d_in[10], (const float*)d_in[14]};
  const float* bx[4] = {(const float*)d_in[3], (const float*)d_in[7], (const float*)d_in[11], (const float*)d_in[15]};
  const float* bh[4] = {(const float*)d_in[4], (const float*)d_in[8], (const float*)d_in[12], (const float*)d_in[16]};
  const float* Wd = (const float*)d_in[17];
  const float* bd = (const float*)d_in[18];

  char* w = (char*)d_ws;
  auto alloc = [&](size_t bytes) {
    char* p = w;
    w += (bytes + 255) & ~(size_t)255;
    return p;
  };
  // total ~72.6 MiB
  __hip_bfloat16* xin = (__hip_bfloat16*)alloc((size_t)TSTEPS * 16 * 128 * 8 * 2);
  __hip_bfloat16* Wp[4];
  Wp[0] = (__hip_bfloat16*)alloc((size_t)64 * 4 * 9 * 4 * 64 * 16);
  for (int l = 1; l < 4; ++l)
    Wp[l] = (__hip_bfloat16*)alloc((size_t)64 * 4 * 16 * 4 * 64 * 16);
  __hip_bfloat16* hout = (__hip_bfloat16*)alloc((size_t)4 * 4 * 128 * 1024 * 2);
  float* hfin = (float*)alloc((size_t)128 * 1024 * 4);
  float* pb = (float*)alloc((size_t)4 * 4096 * 4);
  Sync* sy = (Sync*)alloc(sizeof(Sync));

  prep_xin<<<(TSTEPS * 16 * 128) / 256, 256, 0, stream>>>(inputs, xin);
  for (int l = 0; l < 4; ++l) {
    const int Din = (l == 0) ? 128 : 1024;
    const int KS  = Din + 1024;
    const int KK  = (l == 0) ? 9 : 16;
    const int KQ  = KS / 4;
    prep_w<<<4096, 256, 0, stream>>>(Wx[l], Wh[l], Din, KS, KK, KQ, Wp[l]);
  }
  BiasArgs ba;
  for (int l = 0; l < 4; ++l) { ba.bx[l] = bx[l]; ba.bh[l] = bh[l]; }
  ba.pb = pb;
  prep_bias<<<64, 256, 0, stream>>>(ba);
  prep_zero<<<1025, 256, 0, stream>>>(hout, sy);

  GArgs ga;
  ga.xin = xin;
  for (int l = 0; l < 4; ++l) ga.Wp[l] = Wp[l];
  ga.pb = pb;
  ga.hout = hout;
  ga.hfin = hfin;
  ga.sy = sy;
  ga.Wd = Wd;
  ga.bd = bd;
  ga.out = (float*)d_out;

  // Plain launch: no grid.sync in the kernel since r4; grid(256) x 1 WG/CU
  // co-residency by capacity arithmetic. Cooperative launch was silently
  // rejecting the ~480-VGPR kernel (occupancy query -> 0).
  gru_pipe<<<dim3(256), dim3(256), 0, stream>>>(ga);
}